// Round 3
// baseline (44.352 us; speedup 1.0000x reference)
//
#include <hip/hip_runtime.h>

#define TPB 128   // 2 waves per block

// One thread = one batch element. All three D inputs staged to LDS with
// coalesced float4 loads; cg (wave-uniform) read via scalar loads (SGPRs),
// used directly as the SGPR operand of v_fma. Live VGPR set ~185 < 256 cap.
__global__ __launch_bounds__(TPB, 2) void cg_main_kernel(
    const float* __restrict__ D1, const float* __restrict__ D2,
    const float* __restrict__ D3, const float* __restrict__ cg,
    float* __restrict__ partials)
{
    __shared__ __align__(16) float s_d1[TPB * 9];    //  4.5 KB
    __shared__ __align__(16) float s_d2[TPB * 25];   // 12.5 KB
    __shared__ __align__(16) float s_d3[TPB * 49];   // 24.5 KB

    const int tid = threadIdx.x;
    const int blk = blockIdx.x;

    // ---- coalesced float4 staging (block-contiguous regions, 16B-aligned) ----
    {
        const float4* g = (const float4*)(D1 + (size_t)blk * (TPB * 9));
        float4* s = (float4*)s_d1;
        #pragma unroll
        for (int k = 0; k < 3; ++k) { int i = k * TPB + tid; if (i < TPB * 9 / 4) s[i] = g[i]; }
    }
    {
        const float4* g = (const float4*)(D2 + (size_t)blk * (TPB * 25));
        float4* s = (float4*)s_d2;
        #pragma unroll
        for (int k = 0; k < 7; ++k) { int i = k * TPB + tid; if (i < TPB * 25 / 4) s[i] = g[i]; }
    }
    {
        const float4* g = (const float4*)(D3 + (size_t)blk * (TPB * 49));
        float4* s = (float4*)s_d3;
        #pragma unroll
        for (int k = 0; k < 13; ++k) { int i = k * TPB + tid; if (i < TPB * 49 / 4) s[i] = g[i]; }
    }
    __syncthreads();

    // ---- per-element registers (odd dword strides 9/25/49 -> 2-way = free) ----
    float d1[9];
    #pragma unroll
    for (int i = 0; i < 9; ++i)  d1[i] = s_d1[tid * 9 + i];
    float d2[25];
    #pragma unroll
    for (int j = 0; j < 25; ++j) d2[j] = s_d2[tid * 25 + j];
    float d3[49];
    #pragma unroll
    for (int i = 0; i < 49; ++i) d3[i] = s_d3[tid * 49 + i];

    // ---- U[a][j*7+c] = sum_i d1[a,i] * cg[i,j,c]; cg via uniform scalar loads ----
    float U[3][35];
    #pragma unroll
    for (int j = 0; j < 5; ++j) {
        #pragma unroll
        for (int c = 0; c < 7; ++c) {
            const float c0 = cg[      j * 7 + c];
            const float c1 = cg[35 +  j * 7 + c];
            const float c2 = cg[70 +  j * 7 + c];
            U[0][j * 7 + c] = fmaf(d1[2], c2, fmaf(d1[1], c1, d1[0] * c0));
            U[1][j * 7 + c] = fmaf(d1[5], c2, fmaf(d1[4], c1, d1[3] * c0));
            U[2][j * 7 + c] = fmaf(d1[8], c2, fmaf(d1[7], c1, d1[6] * c0));
        }
    }

    // ---- main contraction: pure FMA on regs + SGPR cg ----
    float acc = 0.0f;
    #pragma unroll
    for (int a = 0; a < 3; ++a) {
        #pragma unroll
        for (int b = 0; b < 5; ++b) {
            #pragma unroll
            for (int c = 0; c < 7; ++c) {
                float L = d2[b * 5] * U[a][c];
                #pragma unroll
                for (int j = 1; j < 5; ++j) L = fmaf(d2[b * 5 + j], U[a][j * 7 + c], L);
                float R = cg[(a * 5 + b) * 7] * d3[c];
                #pragma unroll
                for (int i = 1; i < 7; ++i) R = fmaf(cg[(a * 5 + b) * 7 + i], d3[i * 7 + c], R);
                const float r = L - R;
                acc = fmaf(r, r, acc);
            }
        }
    }

    // ---- block reduce (2 waves) ----
    #pragma unroll
    for (int off = 32; off > 0; off >>= 1)
        acc += __shfl_down(acc, off, 64);
    __shared__ float wsum[TPB / 64];
    if ((tid & 63) == 0) wsum[tid >> 6] = acc;
    __syncthreads();
    if (tid == 0) partials[blk] = wsum[0] + wsum[1];
}

__global__ __launch_bounds__(256) void cg_reduce_kernel(
    const float* __restrict__ partials, float* __restrict__ out,
    int n, float inv)
{
    const int tid = threadIdx.x;
    float s = 0.0f;
    for (int i = tid; i < n; i += 256) s += partials[i];   // deterministic order
    #pragma unroll
    for (int off = 32; off > 0; off >>= 1)
        s += __shfl_down(s, off, 64);
    __shared__ float wsum[4];
    if ((tid & 63) == 0) wsum[tid >> 6] = s;
    __syncthreads();
    if (tid == 0) {
        float t = 0.0f;
        #pragma unroll
        for (int w = 0; w < 4; ++w) t += wsum[w];
        out[0] = t * inv;
    }
}

extern "C" void kernel_launch(void* const* d_in, const int* in_sizes, int n_in,
                              void* d_out, int out_size, void* d_ws, size_t ws_size,
                              hipStream_t stream)
{
    const float* D1 = (const float*)d_in[0];
    const float* D2 = (const float*)d_in[1];
    const float* D3 = (const float*)d_in[2];
    const float* cg = (const float*)d_in[3];
    float* out      = (float*)d_out;
    float* partials = (float*)d_ws;          // 2048 floats = 8 KB scratch

    const int batch   = in_sizes[0] / 9;     // 262144
    const int nblocks = batch / TPB;         // 2048
    const float inv   = 1.0f / ((float)batch * 105.0f);

    cg_main_kernel<<<nblocks, TPB, 0, stream>>>(D1, D2, D3, cg, partials);
    cg_reduce_kernel<<<1, 256, 0, stream>>>(partials, out, nblocks, inv);
}

// Round 4
// 36.038 us; speedup vs baseline: 1.2307x; 1.2307x over previous
//
#include <hip/hip_runtime.h>

#define TPB 64   // one wave per block

// One thread = one batch element. D2/D3 staged to LDS with coalesced float4
// loads (packed linear layout; odd dword strides 25/49 are coprime with 32
// banks -> 2-way aliasing = free). All per-element values are pulled into
// registers ONCE and pinned with empty asm so the compiler cannot sink the
// LDS reads back into the FMA loop (the round-3 failure mode).
__global__ __launch_bounds__(TPB, 1) void cg_main_kernel(
    const float* __restrict__ D1, const float* __restrict__ D2,
    const float* __restrict__ D3, const float* __restrict__ cg,
    float* __restrict__ partials)
{
    __shared__ __align__(16) float s_d2[TPB * 25];   //  6400 B
    __shared__ __align__(16) float s_d3[TPB * 49];   // 12544 B

    const int lane = threadIdx.x;        // 0..63
    const int blk  = blockIdx.x;         // 4096 blocks

    // ---- coalesced float4 staging, packed linear layout ----
    {
        const float4* g = (const float4*)(D2 + (size_t)blk * (TPB * 25)); // blk*6400B, 16B-aligned
        float4* s = (float4*)s_d2;
        #pragma unroll
        for (int k = 0; k < 7; ++k) { int i = k * TPB + lane; if (i < TPB * 25 / 4) s[i] = g[i]; }
    }
    {
        const float4* g = (const float4*)(D3 + (size_t)blk * (TPB * 49)); // blk*12544B, 16B-aligned
        float4* s = (float4*)s_d3;
        #pragma unroll
        for (int k = 0; k < 13; ++k) { int i = k * TPB + lane; if (i < TPB * 49 / 4) s[i] = g[i]; }
    }
    __syncthreads();

    const int x = blk * TPB + lane;

    // ---- pull everything into registers ONCE, then pin ----
    float d1[9];
    {
        const float* p1 = D1 + (size_t)x * 9;   // stride-36B scalar loads, hidden
        #pragma unroll
        for (int i = 0; i < 9; ++i) d1[i] = p1[i];
    }
    float d2[25];
    #pragma unroll
    for (int j = 0; j < 25; ++j) d2[j] = s_d2[lane * 25 + j];
    float d3[49];
    #pragma unroll
    for (int i = 0; i < 49; ++i) d3[i] = s_d3[lane * 49 + i];

    // pin: opaque use+def prevents the compiler from sinking/rematerializing
    // the loads inside the FMA loop (keeps arrays VGPR-resident)
    #pragma unroll
    for (int j = 0; j < 25; ++j) asm volatile("" : "+v"(d2[j]));
    #pragma unroll
    for (int i = 0; i < 49; ++i) asm volatile("" : "+v"(d3[i]));

    // ---- compute: a-outer; cg accessed in contiguous runs so scalar loads merge ----
    float acc = 0.0f;
    #pragma unroll
    for (int a = 0; a < 3; ++a) {
        // Ua[j*7+c] = sum_i d1[a,i] * cg[i*35 + j*7 + c]; i-outer => 35-float
        // contiguous cg run per i (merges into s_load_dwordx8/x16 batches)
        float Ua[35];
        #pragma unroll
        for (int t = 0; t < 35; ++t) Ua[t] = d1[a * 3 + 0] * cg[t];
        #pragma unroll
        for (int t = 0; t < 35; ++t) Ua[t] = fmaf(d1[a * 3 + 1], cg[35 + t], Ua[t]);
        #pragma unroll
        for (int t = 0; t < 35; ++t) Ua[t] = fmaf(d1[a * 3 + 2], cg[70 + t], Ua[t]);

        #pragma unroll
        for (int b = 0; b < 5; ++b) {
            const int cgab = (a * 5 + b) * 7;   // cg[a,b,0..6] contiguous
            #pragma unroll
            for (int c = 0; c < 7; ++c) {
                float L = d2[b * 5] * Ua[c];
                #pragma unroll
                for (int j = 1; j < 5; ++j) L = fmaf(d2[b * 5 + j], Ua[j * 7 + c], L);
                float R = cg[cgab] * d3[c];
                #pragma unroll
                for (int i = 1; i < 7; ++i) R = fmaf(cg[cgab + i], d3[i * 7 + c], R);
                const float r = L - R;
                acc = fmaf(r, r, acc);
            }
        }
    }

    // ---- single-wave butterfly reduce ----
    #pragma unroll
    for (int off = 32; off > 0; off >>= 1)
        acc += __shfl_down(acc, off, 64);
    if (lane == 0) partials[blk] = acc;
}

__global__ __launch_bounds__(256) void cg_reduce_kernel(
    const float* __restrict__ partials, float* __restrict__ out,
    int n, float inv)
{
    const int tid = threadIdx.x;
    float s = 0.0f;
    for (int i = tid; i < n; i += 256) s += partials[i];   // deterministic order
    #pragma unroll
    for (int off = 32; off > 0; off >>= 1)
        s += __shfl_down(s, off, 64);
    __shared__ float wsum[4];
    if ((tid & 63) == 0) wsum[tid >> 6] = s;
    __syncthreads();
    if (tid == 0) {
        float t = 0.0f;
        #pragma unroll
        for (int w = 0; w < 4; ++w) t += wsum[w];
        out[0] = t * inv;
    }
}

extern "C" void kernel_launch(void* const* d_in, const int* in_sizes, int n_in,
                              void* d_out, int out_size, void* d_ws, size_t ws_size,
                              hipStream_t stream)
{
    const float* D1 = (const float*)d_in[0];
    const float* D2 = (const float*)d_in[1];
    const float* D3 = (const float*)d_in[2];
    const float* cg = (const float*)d_in[3];
    float* out      = (float*)d_out;
    float* partials = (float*)d_ws;          // 4096 floats = 16 KB scratch

    const int batch   = in_sizes[0] / 9;     // 262144
    const int nblocks = batch / TPB;         // 4096
    const float inv   = 1.0f / ((float)batch * 105.0f);

    cg_main_kernel<<<nblocks, TPB, 0, stream>>>(D1, D2, D3, cg, partials);
    cg_reduce_kernel<<<1, 256, 0, stream>>>(partials, out, nblocks, inv);
}

// Round 5
// 27.511 us; speedup vs baseline: 1.6122x; 1.3100x over previous
//
#include <hip/hip_runtime.h>

#define TPB 256

// One thread = one batch element; c-outer loop keeps the live register set
// ~60 floats (d1[9], d2[25], d3col[7], U[5], acc) so the compiler keeps it
// resident without pins and occupancy stays high. Only D3 (worst stride,
// 196 B/elem) is staged in LDS; D1/D2 are direct strided loads hidden by TLP.
__global__ __launch_bounds__(TPB, 3) void cg_main_kernel(
    const float* __restrict__ D1, const float* __restrict__ D2,
    const float* __restrict__ D3, const float* __restrict__ cg,
    float* __restrict__ partials)
{
    __shared__ __align__(16) float s_d3[TPB * 49];   // 50176 B -> 3 blocks/CU

    const int tid = threadIdx.x;
    const int blk = blockIdx.x;

    // coalesced float4 staging of the block's D3 region (12544 floats = 3136 float4)
    {
        const float4* g = (const float4*)(D3 + (size_t)blk * (TPB * 49)); // 50176B-aligned
        float4* s = (float4*)s_d3;
        #pragma unroll
        for (int k = 0; k < 13; ++k) {
            int i = k * TPB + tid;
            if (i < TPB * 49 / 4) s[i] = g[i];
        }
    }

    // direct loads for d1/d2 (issued while staging is in flight / at barrier)
    float d1[9], d2[25];
    {
        const float* p1 = D1 + (size_t)(blk * TPB + tid) * 9;
        #pragma unroll
        for (int i = 0; i < 9; ++i) d1[i] = p1[i];
        const float* p2 = D2 + (size_t)(blk * TPB + tid) * 25;
        #pragma unroll
        for (int j = 0; j < 25; ++j) d2[j] = p2[j];
    }
    __syncthreads();

    float acc = 0.0f;
    #pragma unroll
    for (int c = 0; c < 7; ++c) {
        // D3 column c for this element: lane stride 49 dwords (odd) -> 2-way = free
        float d3c[7];
        #pragma unroll
        for (int i = 0; i < 7; ++i) d3c[i] = s_d3[tid * 49 + i * 7 + c];

        #pragma unroll
        for (int a = 0; a < 3; ++a) {
            // U[j] = sum_i d1[a,i] * cg[i,j,c]   (cg is wave-uniform -> SGPRs)
            float U[5];
            #pragma unroll
            for (int j = 0; j < 5; ++j)
                U[j] = fmaf(d1[a * 3 + 2], cg[70 + j * 7 + c],
                       fmaf(d1[a * 3 + 1], cg[35 + j * 7 + c],
                            d1[a * 3 + 0] * cg[      j * 7 + c]));
            #pragma unroll
            for (int b = 0; b < 5; ++b) {
                float L = d2[b * 5] * U[0];
                #pragma unroll
                for (int j = 1; j < 5; ++j) L = fmaf(d2[b * 5 + j], U[j], L);
                float R = cg[(a * 5 + b) * 7] * d3c[0];
                #pragma unroll
                for (int i = 1; i < 7; ++i) R = fmaf(cg[(a * 5 + b) * 7 + i], d3c[i], R);
                const float r = L - R;
                acc = fmaf(r, r, acc);
            }
        }
    }

    // block reduce: wave butterfly + cross-wave LDS
    #pragma unroll
    for (int off = 32; off > 0; off >>= 1)
        acc += __shfl_down(acc, off, 64);
    __shared__ float wsum[TPB / 64];
    if ((tid & 63) == 0) wsum[tid >> 6] = acc;
    __syncthreads();
    if (tid == 0) {
        float s = 0.0f;
        #pragma unroll
        for (int w = 0; w < TPB / 64; ++w) s += wsum[w];
        partials[blk] = s;
    }
}

__global__ __launch_bounds__(256) void cg_reduce_kernel(
    const float* __restrict__ partials, float* __restrict__ out,
    int n, float inv)
{
    const int tid = threadIdx.x;
    float s = 0.0f;
    for (int i = tid; i < n; i += 256) s += partials[i];   // deterministic order
    #pragma unroll
    for (int off = 32; off > 0; off >>= 1)
        s += __shfl_down(s, off, 64);
    __shared__ float wsum[4];
    if ((tid & 63) == 0) wsum[tid >> 6] = s;
    __syncthreads();
    if (tid == 0) {
        float t = 0.0f;
        #pragma unroll
        for (int w = 0; w < 4; ++w) t += wsum[w];
        out[0] = t * inv;
    }
}

extern "C" void kernel_launch(void* const* d_in, const int* in_sizes, int n_in,
                              void* d_out, int out_size, void* d_ws, size_t ws_size,
                              hipStream_t stream)
{
    const float* D1 = (const float*)d_in[0];
    const float* D2 = (const float*)d_in[1];
    const float* D3 = (const float*)d_in[2];
    const float* cg = (const float*)d_in[3];
    float* out      = (float*)d_out;
    float* partials = (float*)d_ws;          // 1024 floats = 4 KB scratch

    const int batch   = in_sizes[0] / 9;     // 262144
    const int nblocks = batch / TPB;         // 1024
    const float inv   = 1.0f / ((float)batch * 105.0f);

    cg_main_kernel<<<nblocks, TPB, 0, stream>>>(D1, D2, D3, cg, partials);
    cg_reduce_kernel<<<1, 256, 0, stream>>>(partials, out, nblocks, inv);
}